// Round 8
// baseline (312.496 us; speedup 1.0000x reference)
//
#include <hip/hip_runtime.h>
#include <hip/hip_bf16.h>
#include <stdint.h>

#define NROWS 131072
#define LMD   1024
#define GNND  200
#define HD    128
#define BLOCK 256
#define MTILE 64
#define NBLK  (NROWS/MTILE)    // 2048
#define WCH   16384            // W chunk bytes (128 h x 64 k bf16)

typedef __attribute__((ext_vector_type(4))) float  f32x4;
typedef __attribute__((ext_vector_type(8))) short  bf16x8;

#define GLDS(SRC, DST) __builtin_amdgcn_global_load_lds( \
    (const __attribute__((address_space(1))) unsigned int*)(SRC), \
    (__attribute__((address_space(3))) unsigned int*)(DST), 16, 0, 0)
#define SCHED0  __builtin_amdgcn_sched_barrier(0)
#define BAR     __builtin_amdgcn_s_barrier()
#define VMW(N)  asm volatile("s_waitcnt vmcnt(" #N ")" ::: "memory")

__device__ __forceinline__ short f2bf(float x) {
    union { __hip_bfloat16 h; short s; } u;
    u.h = __float2bfloat16(x);
    return u.s;
}

__device__ __forceinline__ bf16x8 cvt8(f32x4 a, f32x4 b) {
    bf16x8 r;
    r[0]=f2bf(a[0]); r[1]=f2bf(a[1]); r[2]=f2bf(a[2]); r[3]=f2bf(a[3]);
    r[4]=f2bf(b[0]); r[5]=f2bf(b[1]); r[6]=f2bf(b[2]); r[7]=f2bf(b[3]);
    return r;
}

__device__ __forceinline__ float red16(float v) {
    #pragma unroll
    for (int m=1; m<16; m<<=1) v += __shfl_xor(v, m, 16);
    return v;
}

// ---- prep: K=64 chunk-major, swizzle-baked W panels; also zero the finish counter ----
// W1S[ch][row][e] = bf16(lm_W[kk][row]), kk = ch*64 + (e ^ ((row&7)*8))
__global__ void prep_weights(const float* __restrict__ lm_W,
                             const float* __restrict__ gnn_W,
                             short* __restrict__ W1S, short* __restrict__ W2S,
                             unsigned int* counter)
{
    int idx = blockIdx.x*BLOCK + threadIdx.x;     // 512*256 = 131072 = 16 chunks * 8192 shorts
    if (idx == 0) *counter = 0;
    int row = (idx >> 6) & 127;
    int e   = idx & 63;
    int kk  = (idx >> 13)*64 + (e ^ ((row & 7)*8));
    W1S[idx] = f2bf(lm_W[(long)kk*HD + row]);
    if (idx < 4*8192) {
        W2S[idx] = (kk < GNND) ? f2bf(gnn_W[(long)kk*HD + row]) : (short)0;
    }
}

__global__ __launch_bounds__(BLOCK, 3) void fused(
    const float* __restrict__ lm,  const float* __restrict__ gnn,
    const float* __restrict__ ngn,
    const float* __restrict__ lm_b, const float* __restrict__ gnn_b,
    const char* __restrict__ W1S,  const char* __restrict__ W2S,
    float* partials, unsigned int* counter, float* out)
{
    __shared__ short lbuf[3*8192];      // 48 KB: W bufs 0..2
    __shared__ float bias_lds[256];     // [0..127]=lm_b, [128..255]=gnn_b
    __shared__ float sp[4], sn[4];
    __shared__ int   lastflag;

    const int tid  = threadIdx.x;
    const int lane = tid & 63;
    const int win  = tid >> 6;
    const int col  = lane & 15;
    const int g    = lane >> 4;
    const int wq   = win*4096 + lane*16;           // this wave's staging quarter
    const long row = (long)blockIdx.x * MTILE + win*16 + col;

    const char* aL = (const char*)lm  + row*(LMD*4L)  + g*32;
    const char* aG = (const char*)gnn + row*(GNND*4L) + g*32;
    const char* aN = (const char*)ngn + row*(GNND*4L) + g*32;
    const char* clampG = (const char*)gnn + (size_t)NROWS*GNND*4 - 16;
    const char* clampN = (const char*)ngn + (size_t)NROWS*GNND*4 - 16;

    const float CC   = 1.0f / 11008.0f;
    const float LOGC = -9.3063777f;                // log(1/11008)
    const f32x4 fz = {0.f,0.f,0.f,0.f};

    // stage biases to LDS (drained from FIFO immediately by the ds_write dependency)
    if (tid < 64) {
        f32x4 bv = (tid < 32) ? *(const f32x4*)((const char*)lm_b  + tid*16)
                              : *(const f32x4*)((const char*)gnn_b + (tid-32)*16);
        *(f32x4*)&bias_lds[tid*4] = bv;
    }
    SCHED0;

    // stage W chunk from ws into buf b (4 x 16B per lane; wave covers its quarter)
    auto ISSUEW = [&](const char* ws, int b) {
        const char* s = ws + wq;
        char* d = (char*)lbuf + (size_t)b*WCH + wq;
        #pragma unroll
        for (int i=0;i<4;i++) GLDS(s + i*1024, d + i*1024);
    };
    // load one K=128 A-group (512B per row, 8 x dwordx4 per lane)
    auto LOADG = [&](const char* base, int off, const char* cl, f32x4 (&S)[8]) {
        #pragma unroll
        for (int j=0;j<4;j++) {
            const char* p0 = base + off + j*128;
            const char* p1 = p0 + 16;
            if (cl) { if (p0 > cl) p0 = cl;  if (p1 > cl) p1 = cl; }
            S[2*j]   = *(const f32x4*)p0;
            S[2*j+1] = *(const f32x4*)p1;
        }
    };

    f32x4 SA[8], SB[8];
    f32x4 accL[8], accG[8];
    #pragma unroll
    for (int t=0;t<8;t++) { accL[t] = fz; accG[t] = fz; }

    // one K=64 chunk of MFMA: W from buf c%3, A from SA/SB per c
    auto COMP = [&](int c, f32x4 (&acc)[8]) {
        const short* wb = lbuf + (c % 3)*8192 + col*64;
        const int sw = (col & 7)*8;
        f32x4 (&S)[8] = ((c>>1)&1) ? SB : SA;
        const int half = c & 1;
        #pragma unroll
        for (int ks=0; ks<2; ++ks) {
            bf16x8 af = cvt8(S[half*4 + 2*ks], S[half*4 + 2*ks + 1]);
            const short* cb = wb + ((ks*32 + g*8) ^ sw);
            #pragma unroll
            for (int t=0;t<8;t++) {
                bf16x8 wf = *(const bf16x8*)(cb + t*1024);
                acc[t] = __builtin_amdgcn_mfma_f32_16x16x32_bf16(af, wf, acc[t], 0,0,0);
            }
        }
    };

    float pos_acc = 0.f, neg_acc = 0.f;

    // ---- prologue: W0->b0, W1->b1, Agrp0->SA, Agrp1->SB ----
    ISSUEW(W1S + 0*WCH, 0);
    ISSUEW(W1S + 1*WCH, 1);
    LOADG(aL,   0, nullptr, SA);
    LOADG(aL, 512, nullptr, SB);
    SCHED0; VMW(20); SCHED0; BAR; SCHED0;   // W0 landed; W1 + 16 A in flight

    // ---- chunks 0..19 (16 lm + 4 pos), uniform vmcnt(12) cadence ----
    #pragma unroll
    for (int c = 0; c < 20; ++c) {
        // W issue, 2 ahead
        {
            const char* ws = (c <= 13) ? W1S + (size_t)(c+2)*WCH
                           : (c <= 17) ? W2S + (size_t)(c-14)*WCH
                                       : W2S + (size_t)(c-18)*WCH;
            ISSUEW(ws, (c+2) % 3);
        }
        SCHED0;
        if (c < 16) COMP(c, accL); else COMP(c, accG);
        SCHED0;
        // A refills at odd-chunk ends (set just fully consumed)
        if (c==1)  LOADG(aL, 2*512, nullptr, SA);
        if (c==5)  LOADG(aL, 4*512, nullptr, SA);
        if (c==9)  LOADG(aL, 6*512, nullptr, SA);
        if (c==13) LOADG(aG,     0, clampG,  SA);
        if (c==17) LOADG(aN,     0, clampN,  SA);
        if (c==3)  LOADG(aL, 3*512, nullptr, SB);
        if (c==7)  LOADG(aL, 5*512, nullptr, SB);
        if (c==11) LOADG(aL, 7*512, nullptr, SB);
        if (c==15) LOADG(aG,   512, clampG,  SB);
        if (c==19) LOADG(aN,   512, clampN,  SB);
        SCHED0; VMW(12); SCHED0; BAR; SCHED0;
    }

    // ---- pos epilogue (VALU + LDS only; W21 + A in flight underneath) ----
    float bl[8], bg[8];
    #pragma unroll
    for (int t=0;t<8;t++) { bl[t] = bias_lds[t*16+col]; bg[t] = bias_lds[128+t*16+col]; }
    #pragma unroll
    for (int t=0;t<8;t++) {
        #pragma unroll
        for (int r=0;r<4;r++) accL[t][r] += bl[t];
    }
    #pragma unroll
    for (int r=0;r<4;r++) {
        float lg=0.f, ll=0.f, gg2=0.f;
        #pragma unroll
        for (int t=0;t<8;t++) {
            float lv=accL[t][r], gv=accG[t][r]+bg[t];
            lg += lv*gv; ll += lv*lv; gg2 += gv*gv;
        }
        lg=red16(lg); ll=red16(ll); gg2=red16(gg2);
        float d  = lg * rsqrtf(ll*gg2);
        float pi = d - logf(expf(d)+CC);     // log(ratio)
        if (col==0) pos_acc += pi;
    }
    #pragma unroll
    for (int t=0;t<8;t++) accG[t] = fz;

    // ---- neg chunks 20..23 (W2 restaged; tail waits 12/4/0/none) ----
    #pragma unroll
    for (int c = 20; c < 24; ++c) {
        if (c <= 21) { ISSUEW(W2S + (size_t)(c-18)*WCH, (c+2) % 3); }
        SCHED0;
        COMP(c, accG);
        SCHED0;
        if (c==20)      { VMW(12); SCHED0; BAR; SCHED0; }
        else if (c==21) { VMW(4);  SCHED0; BAR; SCHED0; }
        else if (c==22) { VMW(0);  SCHED0; BAR; SCHED0; }
    }

    // ---- neg epilogue ----
    #pragma unroll
    for (int r=0;r<4;r++) {
        float ln=0.f, nn=0.f, ll=0.f;
        #pragma unroll
        for (int t=0;t<8;t++) {
            float lv=accL[t][r], nv=accG[t][r]+bg[t];
            ln += lv*nv; nn += nv*nv; ll += lv*lv;
        }
        ln=red16(ln); nn=red16(nn); ll=red16(ll);
        float d  = ln * rsqrtf(ll*nn);
        float ni = LOGC - logf(expf(d)+CC);  // log(1-ratio)
        if (col==0) neg_acc += ni;
    }

    // ---- wave + block reduce ----
    #pragma unroll
    for (int m=1;m<64;m<<=1) {
        pos_acc += __shfl_xor(pos_acc, m, 64);
        neg_acc += __shfl_xor(neg_acc, m, 64);
    }
    if (lane==0) { sp[win]=pos_acc; sn[win]=neg_acc; }
    __syncthreads();
    if (tid==0) {
        float p=0.f,n=0.f;
        #pragma unroll
        for (int w=0;w<4;w++){ p+=sp[w]; n+=sn[w]; }
        partials[blockIdx.x*2]   = p;
        partials[blockIdx.x*2+1] = n;
        __threadfence();
        unsigned int old = atomicAdd(counter, 1u);
        lastflag = (old == NBLK - 1) ? 1 : 0;
    }
    __syncthreads();

    // ---- last block: deterministic final reduction ----
    if (lastflag) {
        __threadfence();
        float p = 0.f, n = 0.f;
        for (int i = tid; i < NBLK; i += BLOCK) {
            p += partials[2*i];
            n += partials[2*i+1];
        }
        float* red = (float*)lbuf;       // reuse W LDS
        red[tid] = p; red[BLOCK + tid] = n;
        __syncthreads();
        for (int s = BLOCK/2; s > 0; s >>= 1) {
            if (tid < s) { red[tid] += red[tid+s]; red[BLOCK+tid] += red[BLOCK+tid+s]; }
            __syncthreads();
        }
        if (tid == 0) out[0] = -(red[0] + red[BLOCK]) / (float)NROWS;
    }
}

extern "C" void kernel_launch(void* const* d_in, const int* in_sizes, int n_in,
                              void* d_out, int out_size, void* d_ws, size_t ws_size,
                              hipStream_t stream)
{
    const float* lm    = (const float*)d_in[0];
    const float* gnn   = (const float*)d_in[1];
    const float* ngn   = (const float*)d_in[2];
    const float* lm_W  = (const float*)d_in[3];
    const float* lm_b  = (const float*)d_in[4];
    const float* gnn_W = (const float*)d_in[5];
    const float* gnn_b = (const float*)d_in[6];

    short* W1S = (short*)d_ws;                                     // 16*16384 = 262144 B
    short* W2S = (short*)((char*)d_ws + 262144);                   //  4*16384 =  65536 B
    float* partials = (float*)((char*)d_ws + 262144 + 65536);      // 16 KB
    unsigned int* counter = (unsigned int*)((char*)d_ws + 262144 + 65536 + 16384);

    prep_weights<<<512, BLOCK, 0, stream>>>(lm_W, gnn_W, W1S, W2S, counter);
    fused<<<NBLK, BLOCK, 0, stream>>>(lm, gnn, ngn, lm_b, gnn_b,
                                      (const char*)W1S, (const char*)W2S,
                                      partials, counter, (float*)d_out);
}

// Round 9
// 178.535 us; speedup vs baseline: 1.7503x; 1.7503x over previous
//
#include <hip/hip_runtime.h>
#include <hip/hip_bf16.h>
#include <stdint.h>

#define NROWS 131072
#define LMD   1024
#define GNND  200
#define HD    128
#define BLOCK 256
#define MTILE 64
#define NBLK  (NROWS/MTILE)    // 2048
#define WCH   16384            // W chunk bytes (128 h x 64 k bf16)

typedef __attribute__((ext_vector_type(4))) float  f32x4;
typedef __attribute__((ext_vector_type(8))) short  bf16x8;

#define GLDS(SRC, DST) __builtin_amdgcn_global_load_lds( \
    (const __attribute__((address_space(1))) unsigned int*)(SRC), \
    (__attribute__((address_space(3))) unsigned int*)(DST), 16, 0, 0)
#define SCHED0  __builtin_amdgcn_sched_barrier(0)
#define BAR     __builtin_amdgcn_s_barrier()
#define VMW(N)  asm volatile("s_waitcnt vmcnt(" #N ")" ::: "memory")

__device__ __forceinline__ short f2bf(float x) {
    union { __hip_bfloat16 h; short s; } u;
    u.h = __float2bfloat16(x);
    return u.s;
}

__device__ __forceinline__ bf16x8 cvt8(f32x4 a, f32x4 b) {
    bf16x8 r;
    r[0]=f2bf(a[0]); r[1]=f2bf(a[1]); r[2]=f2bf(a[2]); r[3]=f2bf(a[3]);
    r[4]=f2bf(b[0]); r[5]=f2bf(b[1]); r[6]=f2bf(b[2]); r[7]=f2bf(b[3]);
    return r;
}

__device__ __forceinline__ float red16(float v) {
    #pragma unroll
    for (int m=1; m<16; m<<=1) v += __shfl_xor(v, m, 16);
    return v;
}

// ---- prep: K=64 chunk-major, swizzle-baked W panels ----
// W1S[ch][row][e] = bf16(lm_W[kk][row]), kk = ch*64 + (e ^ ((row&7)*8))
__global__ void prep_weights(const float* __restrict__ lm_W,
                             const float* __restrict__ gnn_W,
                             short* __restrict__ W1S, short* __restrict__ W2S)
{
    int idx = blockIdx.x*BLOCK + threadIdx.x;     // 512*256 = 131072 = 16 chunks * 8192 shorts
    int row = (idx >> 6) & 127;
    int e   = idx & 63;
    int kk  = (idx >> 13)*64 + (e ^ ((row & 7)*8));
    W1S[idx] = f2bf(lm_W[(long)kk*HD + row]);
    if (idx < 4*8192) {
        W2S[idx] = (kk < GNND) ? f2bf(gnn_W[(long)kk*HD + row]) : (short)0;
    }
}

__global__ __launch_bounds__(BLOCK) void fused(
    const float* __restrict__ lm,  const float* __restrict__ gnn,
    const float* __restrict__ ngn,
    const float* __restrict__ lm_b, const float* __restrict__ gnn_b,
    const char* __restrict__ W1S,  const char* __restrict__ W2S,
    float* __restrict__ partials)
{
    __shared__ short lbuf[4*8192];      // 64 KB: W bufs b0..b3
    __shared__ float sp[4], sn[4];

    const int tid  = threadIdx.x;
    const int lane = tid & 63;
    const int win  = tid >> 6;
    const int col  = lane & 15;
    const int g    = lane >> 4;
    const int wq   = win*4096 + lane*16;           // this wave's staging quarter
    const long row = (long)blockIdx.x * MTILE + win*16 + col;
    const int rotg = blockIdx.x & 7;               // k-phase rotation (HBM channel de-conflict)

    const char* aL = (const char*)lm  + row*(LMD*4L)  + g*32;
    const char* aG = (const char*)gnn + row*(GNND*4L) + g*32;
    const char* aN = (const char*)ngn + row*(GNND*4L) + g*32;
    const char* clampG = (const char*)gnn + (size_t)NROWS*GNND*4 - 16;
    const char* clampN = (const char*)ngn + (size_t)NROWS*GNND*4 - 16;

    const float CC   = 1.0f / 11008.0f;
    const float LOGC = -9.3063777f;                // log(1/11008)
    const f32x4 fz = {0.f,0.f,0.f,0.f};

    // rotated lm A-group byte offset for logical group of physical group p
    auto LOFF = [&](int p)->int { return ((p + rotg) & 7) * 512; };
    // rotated W source for physical chunk p
    auto WSRC = [&](int p)->const char* {
        if (p < 16) {
            int lc = 2*(((p >> 1) + rotg) & 7) + (p & 1);
            return W1S + (size_t)lc*WCH;
        }
        return W2S + (size_t)(p - 16)*WCH;
    };

    // stage W chunk from ws into buf b (4 x 16B per lane; wave covers its quarter)
    auto ISSUEW = [&](const char* ws, int b) {
        const char* s = ws + wq;
        char* d = (char*)lbuf + (size_t)b*WCH + wq;
        #pragma unroll
        for (int i=0;i<4;i++) GLDS(s + i*1024, d + i*1024);
    };
    // load one K=128 A-group (512B per row, 8 x dwordx4 per lane)
    auto LOADG = [&](const char* base, int off, const char* cl, f32x4 (&S)[8]) {
        #pragma unroll
        for (int j=0;j<4;j++) {
            const char* p0 = base + off + j*128;
            const char* p1 = p0 + 16;
            if (cl) { if (p0 > cl) p0 = cl;  if (p1 > cl) p1 = cl; }
            S[2*j]   = *(const f32x4*)p0;
            S[2*j+1] = *(const f32x4*)p1;
        }
    };
    // one K=64 chunk of MFMA: W from buf c&3, A from slots S[half*4 .. half*4+3]
    auto COMP = [&](int c, int half, f32x4 (&S)[8], f32x4 (&acc)[8]) {
        const short* wb = lbuf + (c & 3)*8192 + col*64;
        const int sw = (col & 7)*8;
        #pragma unroll
        for (int ks=0; ks<2; ++ks) {
            bf16x8 af = cvt8(S[half*4 + 2*ks], S[half*4 + 2*ks + 1]);
            const short* cb = wb + ((ks*32 + g*8) ^ sw);
            #pragma unroll
            for (int t=0;t<8;t++) {
                bf16x8 wf = *(const bf16x8*)(cb + t*1024);
                acc[t] = __builtin_amdgcn_mfma_f32_16x16x32_bf16(af, wf, acc[t], 0,0,0);
            }
        }
    };

    f32x4 accL[8], accG[8];
    #pragma unroll
    for (int t=0;t<8;t++) accL[t] = fz;
    f32x4 SA[8], SB[8];
    float pos_acc = 0.f, neg_acc = 0.f;

    // ---- prologue: biases first (drained at first wait), then W0-2, Agrp0-1 ----
    float bl[8], bg[8];
    #pragma unroll
    for (int t=0;t<8;t++) bl[t] = lm_b[t*16+col];
    #pragma unroll
    for (int t=0;t<8;t++) bg[t] = gnn_b[t*16+col];
    SCHED0;
    ISSUEW(WSRC(0), 0); ISSUEW(WSRC(1), 1); ISSUEW(WSRC(2), 2);
    LOADG(aL, LOFF(0), nullptr, SA);
    LOADG(aL, LOFF(1), nullptr, SB);
    SCHED0; VMW(24); SCHED0; BAR; SCHED0;
    #pragma unroll
    for (int t=0;t<8;t++) { asm volatile("" : "+v"(bl[t])); asm volatile("" : "+v"(bg[t])); }

    // ---- lm phase: groups 0..7 (chunks 0..15) ----
    #pragma unroll
    for (int gg=0; gg<8; ++gg) {
        f32x4 (&S)[8] = (gg & 1) ? SB : SA;
        // even chunk 2gg
        ISSUEW(WSRC(2*gg+3), (2*gg+3) & 3);
        SCHED0;
        COMP(2*gg, 0, S, accL);
        SCHED0; VMW(16); SCHED0; BAR; SCHED0;
        // odd chunk 2gg+1
        ISSUEW(WSRC(2*gg+4), (2*gg+4) & 3);
        SCHED0;
        COMP(2*gg+1, 1, S, accL);
        SCHED0;
        if (gg < 6)       LOADG(aL, LOFF(gg+2), nullptr, S);   // grp gg+2 (lm, rotated)
        else if (gg == 6) LOADG(aG,   0, clampG, S);           // grp 8 (gnn)
        else              LOADG(aG, 512, clampG, S);           // grp 9 (gnn)
        SCHED0; VMW(24); SCHED0; BAR; SCHED0;
    }

    // lm bias epilogue
    #pragma unroll
    for (int t=0;t<8;t++) {
        #pragma unroll
        for (int r=0;r<4;r++) accL[t][r] += bl[t];
    }
    #pragma unroll
    for (int t=0;t<8;t++) accG[t] = fz;

    // ---- pos phase: chunks 16..19 ----
    ISSUEW(WSRC(19), 3);
    SCHED0;
    COMP(16, 0, SA, accG);
    SCHED0; VMW(16); SCHED0; BAR; SCHED0;

    COMP(17, 1, SA, accG);
    SCHED0;
    LOADG(aN, 0, clampN, SA);                                  // grp 10 (ngn)
    SCHED0; VMW(20); SCHED0; BAR; SCHED0;

    COMP(18, 0, SB, accG);
    SCHED0; VMW(8); SCHED0; BAR; SCHED0;

    COMP(19, 1, SB, accG);
    SCHED0;
    LOADG(aN, 512, clampN, SB);                                // grp 11 (ngn)
    SCHED0;
    // no wait / no barrier from here on: W2 resident in b0..b3, no LDS writes left

    // pos epilogue (A grp10/11 in flight underneath)
    #pragma unroll
    for (int r=0;r<4;r++) {
        float lg=0.f, ll=0.f, gg2=0.f;
        #pragma unroll
        for (int t=0;t<8;t++) {
            float lv=accL[t][r], gv=accG[t][r]+bg[t];
            lg += lv*gv; ll += lv*lv; gg2 += gv*gv;
        }
        lg=red16(lg); ll=red16(ll); gg2=red16(gg2);
        float d  = lg * rsqrtf(ll*gg2);
        float pi = d - logf(expf(d)+CC);     // log(ratio)
        if (col==0) pos_acc += pi;
    }
    #pragma unroll
    for (int t=0;t<8;t++) accG[t] = fz;

    // ---- neg phase: chunks 20..23 (barrier-free, desynced) ----
    COMP(20, 0, SA, accG);
    COMP(21, 1, SA, accG);
    COMP(22, 0, SB, accG);
    COMP(23, 1, SB, accG);

    // neg epilogue
    #pragma unroll
    for (int r=0;r<4;r++) {
        float ln=0.f, nn=0.f, ll=0.f;
        #pragma unroll
        for (int t=0;t<8;t++) {
            float lv=accL[t][r], nv=accG[t][r]+bg[t];
            ln += lv*nv; nn += nv*nv; ll += lv*lv;
        }
        ln=red16(ln); nn=red16(nn); ll=red16(ll);
        float d  = ln * rsqrtf(ll*nn);
        float ni = LOGC - logf(expf(d)+CC);  // log(1-ratio)
        if (col==0) neg_acc += ni;
    }

    // ---- wave + block reduce ----
    #pragma unroll
    for (int m=1;m<64;m<<=1) {
        pos_acc += __shfl_xor(pos_acc, m, 64);
        neg_acc += __shfl_xor(neg_acc, m, 64);
    }
    if (lane==0) { sp[win]=pos_acc; sn[win]=neg_acc; }
    __syncthreads();
    if (tid==0) {
        float p=0.f,n=0.f;
        #pragma unroll
        for (int w=0;w<4;w++){ p+=sp[w]; n+=sn[w]; }
        partials[blockIdx.x*2]   = p;
        partials[blockIdx.x*2+1] = n;
    }
}

__global__ void finalize(const float* __restrict__ partials, float* __restrict__ out)
{
    __shared__ float sp[BLOCK], sn[BLOCK];
    float p=0.f, n=0.f;
    for (int i=threadIdx.x; i<NBLK; i+=BLOCK) { p += partials[2*i]; n += partials[2*i+1]; }
    sp[threadIdx.x]=p; sn[threadIdx.x]=n;
    __syncthreads();
    for (int s=BLOCK/2; s>0; s>>=1) {
        if (threadIdx.x < s) { sp[threadIdx.x]+=sp[threadIdx.x+s]; sn[threadIdx.x]+=sn[threadIdx.x+s]; }
        __syncthreads();
    }
    if (threadIdx.x==0) out[0] = -(sp[0]+sn[0]) / (float)NROWS;
}

extern "C" void kernel_launch(void* const* d_in, const int* in_sizes, int n_in,
                              void* d_out, int out_size, void* d_ws, size_t ws_size,
                              hipStream_t stream)
{
    const float* lm    = (const float*)d_in[0];
    const float* gnn   = (const float*)d_in[1];
    const float* ngn   = (const float*)d_in[2];
    const float* lm_W  = (const float*)d_in[3];
    const float* lm_b  = (const float*)d_in[4];
    const float* gnn_W = (const float*)d_in[5];
    const float* gnn_b = (const float*)d_in[6];

    short* W1S = (short*)d_ws;                                   // 16*16384 = 262144 B
    short* W2S = (short*)((char*)d_ws + 262144);                 //  4*16384 =  65536 B
    float* partials = (float*)((char*)d_ws + 262144 + 65536);    // 16 KB

    prep_weights<<<512, BLOCK, 0, stream>>>(lm_W, gnn_W, W1S, W2S);
    fused<<<NBLK, BLOCK, 0, stream>>>(lm, gnn, ngn, lm_b, gnn_b,
                                      (const char*)W1S, (const char*)W2S, partials);
    finalize<<<1, BLOCK, 0, stream>>>(partials, (float*)d_out);
}